// Round 2
// baseline (226.985 us; speedup 1.0000x reference)
//
#include <hip/hip_runtime.h>
#include <hip/hip_bf16.h>
#include <stdint.h>

// MultiHeadAttention: B=2, P=2048, D_MODEL=1024, H=16, D=64, causal.
//
// R13: (a) attn_k: 32 q-rows per wave (QBLK=128) — K/V LDS fragment reads
// amortized over 2 row-groups (kernel was LDS-BW-bound: 2214 cyc/iter
// measured ~= 144KB/iter LDS reads at 85B/cyc). q-tile pairs (qt,15-qt)
// -> 256 balanced blocks, kt-iters halve. P slab stride 80 (conflict-free
// for b16 scatter writes AND b128 reads; 72 made writes 4-way = the
// residual 4.87M conflicts). (b) gemm128_core: reg-staging replaced by
// __builtin_amdgcn_global_load_lds width=16 (m93->m97 ladder, +69%),
// linear LDS [128][64] as required by the wave-uniform-base DMA.

typedef __bf16 bf16x8 __attribute__((ext_vector_type(8)));
typedef float f32x4 __attribute__((ext_vector_type(4)));
typedef unsigned short u16;

__device__ __forceinline__ u16 f2bf(float f) {
  unsigned u = __float_as_uint(f);
  u += 0x7fffu + ((u >> 16) & 1u);
  return (u16)(u >> 16);
}

// ---- X f32 -> bf16 (coalesced, 8 elems/thread) ----
__global__ __launch_bounds__(256) void xcvt_k(const float* __restrict__ in,
                                              u16* __restrict__ out) {
  int i = (blockIdx.x * 256 + threadIdx.x) * 8;
  float4 f0 = *reinterpret_cast<const float4*>(in + i);
  float4 f1 = *reinterpret_cast<const float4*>(in + i + 4);
  u16 tmp[8] = {f2bf(f0.x), f2bf(f0.y), f2bf(f0.z), f2bf(f0.w),
                f2bf(f1.x), f2bf(f1.y), f2bf(f1.z), f2bf(f1.w)};
  *reinterpret_cast<uint4*>(out + i) = *reinterpret_cast<uint4*>(tmp);
}

// ---- generic weight transpose+convert: in f32 [B][R][C] -> out bf16 [B][C][R] ----
__global__ __launch_bounds__(256) void transpose_cvt_k(const float* __restrict__ in,
                                                       u16* __restrict__ out,
                                                       int R, int C) {
  __shared__ u16 tile[64][80];
  int b = blockIdx.z;
  int r0 = blockIdx.x * 64, c0 = blockIdx.y * 64;
  const float* ip = in + (size_t)b * R * C;
  u16* op = out + (size_t)b * R * C;
  int t = threadIdx.x;
  int r = t >> 2, cb = (t & 3) * 16;
  const float4* src = reinterpret_cast<const float4*>(ip + (size_t)(r0 + r) * C + c0 + cb);
  u16 tmp[16];
#pragma unroll
  for (int v = 0; v < 4; v++) {
    float4 f = src[v];
    tmp[v * 4 + 0] = f2bf(f.x);
    tmp[v * 4 + 1] = f2bf(f.y);
    tmp[v * 4 + 2] = f2bf(f.z);
    tmp[v * 4 + 3] = f2bf(f.w);
  }
  *reinterpret_cast<uint4*>(&tile[r][cb]) = *reinterpret_cast<uint4*>(&tmp[0]);
  *reinterpret_cast<uint4*>(&tile[r][cb + 8]) = *reinterpret_cast<uint4*>(&tmp[8]);
  __syncthreads();
  int c = t >> 2, rb = (t & 3) * 16;
  uint4 outv[2];
  u16* tp = reinterpret_cast<u16*>(outv);
#pragma unroll
  for (int j = 0; j < 16; j++) tp[j] = tile[rb + j][c];
  uint4* dst = reinterpret_cast<uint4*>(op + (size_t)(c0 + c) * R + r0 + rb);
  dst[0] = outv[0];
  dst[1] = outv[1];
}

// ---- fused q/k/v weight transpose: z = 0..47 -> (sel = z>>4, head = z&15) ----
__global__ __launch_bounds__(256) void transpose_qkv_k(const float* __restrict__ Wq,
                                                       const float* __restrict__ Wk,
                                                       const float* __restrict__ Wv,
                                                       u16* __restrict__ outBase) {
  __shared__ u16 tile[64][80];
  int z = blockIdx.z;
  int sel = z >> 4, head = z & 15;
  const float* W = (sel == 0) ? Wq : (sel == 1 ? Wk : Wv);
  const float* ip = W + (size_t)head * 65536;           // [1024][64]
  u16* op = outBase + (size_t)sel * 1048576 + (size_t)head * 65536;  // [64][1024]
  int r0 = blockIdx.x * 64;                              // row block in R=1024
  int t = threadIdx.x;
  int r = t >> 2, cb = (t & 3) * 16;
  const float4* src = reinterpret_cast<const float4*>(ip + (size_t)(r0 + r) * 64 + cb);
  u16 tmp[16];
#pragma unroll
  for (int v = 0; v < 4; v++) {
    float4 f = src[v];
    tmp[v * 4 + 0] = f2bf(f.x);
    tmp[v * 4 + 1] = f2bf(f.y);
    tmp[v * 4 + 2] = f2bf(f.z);
    tmp[v * 4 + 3] = f2bf(f.w);
  }
  *reinterpret_cast<uint4*>(&tile[r][cb]) = *reinterpret_cast<uint4*>(&tmp[0]);
  *reinterpret_cast<uint4*>(&tile[r][cb + 8]) = *reinterpret_cast<uint4*>(&tmp[8]);
  __syncthreads();
  int c = t >> 2, rb = (t & 3) * 16;
  uint4 outv[2];
  u16* tp = reinterpret_cast<u16*>(outv);
#pragma unroll
  for (int j = 0; j < 16; j++) tp[j] = tile[rb + j][c];
  uint4* dst = reinterpret_cast<uint4*>(op + (size_t)c * 1024 + r0 + rb);
  dst[0] = outv[0];
  dst[1] = outv[1];
}

// ---- direct global->LDS DMA, 16B per lane (dest = wave-uniform base + lane*16) ----
__device__ __forceinline__ void gload16(const u16* g, u16* l) {
  __builtin_amdgcn_global_load_lds(
      (__attribute__((address_space(1))) void*)(g),
      (__attribute__((address_space(3))) void*)(l), 16, 0, 0);
}

// ================= 128x128 GEMM core (m97 rung: global_load_lds) =================
__device__ __forceinline__ void gemm128_core(const u16* __restrict__ A,
                                             const u16* __restrict__ BT,
                                             int m0, int n0,
                                             f32x4 (&acc)[4][4]) {
  __shared__ __align__(16) u16 As[128][64];
  __shared__ __align__(16) u16 Bs[128][64];
  int t = threadIdx.x, l = t & 63;
  int w = t >> 6, wm = w & 1, wn = w >> 1;
  int l15 = l & 15, q4 = l >> 4;
  // staging: wave w covers rows [w*32, w*32+32); instr i covers 8 rows;
  // lane l -> row +(l>>3), 16B chunk (l&7)*8 elems. LDS dest is linear.
  int srow = w * 32 + (l >> 3);
  int scol = (l & 7) * 8;
  const u16* ga = A + (size_t)(m0 + srow) * 1024 + scol;
  const u16* gb = BT + (size_t)(n0 + srow) * 1024 + scol;
  f32x4 z4 = {0.f, 0.f, 0.f, 0.f};
#pragma unroll
  for (int mi = 0; mi < 4; mi++)
#pragma unroll
    for (int nt = 0; nt < 4; nt++) acc[mi][nt] = z4;

  for (int k0 = 0; k0 < 1024; k0 += 64) {
    __syncthreads();
#pragma unroll
    for (int i = 0; i < 4; i++) {
      gload16(ga + (size_t)(i * 8) * 1024 + k0, &As[w * 32 + i * 8][0]);
      gload16(gb + (size_t)(i * 8) * 1024 + k0, &Bs[w * 32 + i * 8][0]);
    }
    __syncthreads();   // compiler inserts vmcnt(0) drain before the barrier
#pragma unroll
    for (int kk = 0; kk < 2; kk++) {
      bf16x8 af[4], bfr[4];
#pragma unroll
      for (int mi = 0; mi < 4; mi++)
        af[mi] = *reinterpret_cast<const bf16x8*>(&As[wm * 64 + mi * 16 + l15][kk * 32 + q4 * 8]);
#pragma unroll
      for (int nt = 0; nt < 4; nt++)
        bfr[nt] = *reinterpret_cast<const bf16x8*>(&Bs[wn * 64 + nt * 16 + l15][kk * 32 + q4 * 8]);
#pragma unroll
      for (int mi = 0; mi < 4; mi++)
#pragma unroll
        for (int nt = 0; nt < 4; nt++)
          acc[mi][nt] = __builtin_amdgcn_mfma_f32_16x16x32_bf16(af[mi], bfr[nt], acc[mi][nt], 0, 0, 0);
    }
  }
}

// QKV: A=Xb [4096][1024], BT=[WqT|WkT|WvT] [3072][1024]; grid (32, 24).
// V written tile-blocked: VT2[bh][ktile(32)][d(64)][pc(64)].
__global__ __launch_bounds__(256) void qkv_gemm128_k(const u16* __restrict__ A,
                                                     const u16* __restrict__ BT,
                                                     u16* __restrict__ Q,
                                                     u16* __restrict__ K,
                                                     u16* __restrict__ VT2) {
  const float QSCALE = 0.125f * 1.44269504088896340736f;  // (1/sqrt(64))*log2(e)
  int m0 = blockIdx.x * 128, n0 = blockIdx.y * 128;
  f32x4 acc[4][4];
  gemm128_core(A, BT, m0, n0, acc);
  int t = threadIdx.x, l = t & 63;
  int w = t >> 6, wm = w & 1, wn = w >> 1;
  int l15 = l & 15, q4 = l >> 4;
#pragma unroll
  for (int mi = 0; mi < 4; mi++) {
#pragma unroll
    for (int nt = 0; nt < 4; nt++) {
#pragma unroll
      for (int r = 0; r < 4; r++) {
        int m = m0 + wm * 64 + mi * 16 + q4 * 4 + r;
        int n = n0 + wn * 64 + nt * 16 + l15;
        int wsel = n >> 10, h = (n >> 6) & 15, d = n & 63;
        int b = m >> 11, p = m & 2047;
        size_t bh = (size_t)(b * 16 + h);
        float v = acc[mi][nt][r];
        if (wsel == 0)
          Q[(bh * 2048 + p) * 64 + d] = f2bf(v * QSCALE);
        else if (wsel == 1)
          K[(bh * 2048 + p) * 64 + d] = f2bf(v);
        else
          VT2[((bh * 32 + (p >> 6)) * 64 + d) * 64 + (p & 63)] = f2bf(v);
      }
    }
  }
}

// OUT: A=Ab [4096][1024], BT=WoT [1024][1024], O f32; grid (32, 8).
__global__ __launch_bounds__(256) void out_gemm128_k(const u16* __restrict__ A,
                                                     const u16* __restrict__ BT,
                                                     float* __restrict__ O) {
  int m0 = blockIdx.x * 128, n0 = blockIdx.y * 128;
  f32x4 acc[4][4];
  gemm128_core(A, BT, m0, n0, acc);
  int t = threadIdx.x, l = t & 63;
  int w = t >> 6, wm = w & 1, wn = w >> 1;
  int l15 = l & 15, q4 = l >> 4;
#pragma unroll
  for (int mi = 0; mi < 4; mi++) {
#pragma unroll
    for (int nt = 0; nt < 4; nt++) {
#pragma unroll
      for (int r = 0; r < 4; r++) {
        int m = m0 + wm * 64 + mi * 16 + q4 * 4 + r;
        int n = n0 + wn * 64 + nt * 16 + l15;
        O[(size_t)m * 1024 + n] = acc[mi][nt][r];
      }
    }
  }
}

// ---------------- flash attention: QBLK=128, 32 q-rows/wave ----------------
// grid (8 qtile-pairs, 16 heads, 2 batch); block does qt=pr then qt=15-pr
// (34 kt-iters total, perfectly balanced; 256 blocks = 1/CU).
// Per kt-iter: issue next K/V tile's global loads -> QK (each K fragment
// feeds 2 row-group MFMAs) -> softmax -> PV -> land next tile -> 1 barrier.
__global__ __launch_bounds__(256) void attn_k(const u16* __restrict__ Q,
                                              const u16* __restrict__ K,
                                              const u16* __restrict__ VT2,
                                              u16* __restrict__ A) {
  __shared__ u16 Ks[2][64][72];
  __shared__ u16 Vs[2][64][72];
  __shared__ u16 P[4][32][80];   // wave-private; stride 80: b16-write & b128-read conflict-free
  int pr = blockIdx.x, h = blockIdx.y, b = blockIdx.z;
  size_t bh = (size_t)(b * 16 + h);
  const u16* Qp = Q + bh * 2048 * 64;
  const u16* Kp = K + bh * 2048 * 64;
  const u16* Vt = VT2 + bh * 32 * 64 * 64;   // [kt][d][64]
  int t = threadIdx.x, l = t & 63, w = t >> 6;
  int l15 = l & 15, q4 = l >> 4;
  const float NEG = -1e30f;
  f32x4 z4 = {0.f, 0.f, 0.f, 0.f};
  // staging: threads 0..127 -> K tile, 128..255 -> V tile; 64B each.
  int srow = (t & 127) >> 1, shalf = t & 1;
  bool isV = t >= 128;
  const u16* sbase = (isV ? Vt : Kp) + (size_t)srow * 64 + shalf * 32;

#pragma unroll
  for (int which = 0; which < 2; which++) {
    int qt = which ? (15 - pr) : pr;    // 128-row q tile index
    int nkt = 2 * qt + 2;               // 64-row kv tiles covering rows < (qt+1)*128
    int qr0 = qt * 128 + w * 32;
    bf16x8 qf[2][2];
#pragma unroll
    for (int mi = 0; mi < 2; mi++) {
      const u16* qp = Qp + (size_t)(qr0 + mi * 16 + l15) * 64;
      qf[mi][0] = *reinterpret_cast<const bf16x8*>(qp + q4 * 8);
      qf[mi][1] = *reinterpret_cast<const bf16x8*>(qp + 32 + q4 * 8);
    }
    f32x4 accO[2][4];
    float rs[2][4];
#pragma unroll
    for (int mi = 0; mi < 2; mi++) {
#pragma unroll
      for (int nt = 0; nt < 4; nt++) accO[mi][nt] = z4;
#pragma unroll
      for (int r = 0; r < 4; r++) rs[mi][r] = 0.f;
    }

    // prologue: stage tile kt=0 into buffer 0 (all prior LDS reads retired
    // at the previous pass's trailing barrier; epilogue touches no LDS)
    {
      const uint4* s4 = reinterpret_cast<const uint4*>(sbase);
      uint4 v0 = s4[0], v1 = s4[1], v2 = s4[2], v3 = s4[3];
      uint4* d4 = isV ? reinterpret_cast<uint4*>(&Vs[0][srow][shalf * 32])
                      : reinterpret_cast<uint4*>(&Ks[0][srow][shalf * 32]);
      d4[0] = v0; d4[1] = v1; d4[2] = v2; d4[3] = v3;
    }
    __syncthreads();

    for (int kt = 0; kt < nkt; kt++) {
      int cur = kt & 1;
      bool more = kt < nkt - 1;
      uint4 n0, n1, n2, n3;
      if (more) {  // issue next tile's loads EARLY; latency hides under compute
        const uint4* s4 = reinterpret_cast<const uint4*>(sbase + (size_t)(kt + 1) * 4096);
        n0 = s4[0]; n1 = s4[1]; n2 = s4[2]; n3 = s4[3];
      }

      f32x4 s[2][4];
#pragma unroll
      for (int mi = 0; mi < 2; mi++)
#pragma unroll
        for (int nt = 0; nt < 4; nt++) s[mi][nt] = z4;
      __builtin_amdgcn_s_setprio(1);
#pragma unroll
      for (int kk = 0; kk < 2; kk++) {
        bf16x8 kf[4];
#pragma unroll
        for (int nt = 0; nt < 4; nt++)
          kf[nt] = *reinterpret_cast<const bf16x8*>(&Ks[cur][nt * 16 + l15][kk * 32 + q4 * 8]);
#pragma unroll
        for (int mi = 0; mi < 2; mi++)
#pragma unroll
          for (int nt = 0; nt < 4; nt++)
            s[mi][nt] = __builtin_amdgcn_mfma_f32_16x16x32_bf16(qf[mi][kk], kf[nt], s[mi][nt], 0, 0, 0);
      }
      __builtin_amdgcn_s_setprio(0);
      if (kt >= 2 * qt) {  // causal masking (last two kv tiles of this q tile)
        int colbase = (kt - 2 * qt) * 64;   // 0 or 64, in 128-row-tile coords
        int rowl = w * 32 + q4 * 4;
#pragma unroll
        for (int mi = 0; mi < 2; mi++)
#pragma unroll
          for (int nt = 0; nt < 4; nt++)
#pragma unroll
            for (int r = 0; r < 4; r++)
              if (colbase + nt * 16 + l15 > rowl + mi * 16 + r) s[mi][nt][r] = NEG;
      }
      // fixed-max softmax numerator: p = 2^s (s already log2-domain)
#pragma unroll
      for (int mi = 0; mi < 2; mi++)
#pragma unroll
        for (int nt = 0; nt < 4; nt++)
#pragma unroll
          for (int r = 0; r < 4; r++) {
            float p = exp2f(s[mi][nt][r]);
            rs[mi][r] += p;
            P[w][mi * 16 + q4 * 4 + r][nt * 16 + l15] = f2bf(p);
          }
      __builtin_amdgcn_s_setprio(1);
#pragma unroll
      for (int kk = 0; kk < 2; kk++) {
        bf16x8 pa[2];
#pragma unroll
        for (int mi = 0; mi < 2; mi++)
          pa[mi] = *reinterpret_cast<const bf16x8*>(&P[w][mi * 16 + l15][kk * 32 + q4 * 8]);
#pragma unroll
        for (int nt = 0; nt < 4; nt++) {
          bf16x8 vf = *reinterpret_cast<const bf16x8*>(&Vs[cur][nt * 16 + l15][kk * 32 + q4 * 8]);
#pragma unroll
          for (int mi = 0; mi < 2; mi++)
            accO[mi][nt] = __builtin_amdgcn_mfma_f32_16x16x32_bf16(pa[mi], vf, accO[mi][nt], 0, 0, 0);
        }
      }
      __builtin_amdgcn_s_setprio(0);

      if (more) {  // land next tile into the other buffer (read last at kt-1)
        uint4* d4 = isV ? reinterpret_cast<uint4*>(&Vs[cur ^ 1][srow][shalf * 32])
                        : reinterpret_cast<uint4*>(&Ks[cur ^ 1][srow][shalf * 32]);
        d4[0] = n0; d4[1] = n1; d4[2] = n2; d4[3] = n3;
      }
      __syncthreads();  // single barrier per iteration
    }
#pragma unroll
    for (int mi = 0; mi < 2; mi++)
#pragma unroll
      for (int r = 0; r < 4; r++) {
        float v = rs[mi][r];
#pragma unroll
        for (int sh = 1; sh < 16; sh <<= 1) v += __shfl_xor(v, sh, 64);
        float inv = 1.f / v;
        int prow = qt * 128 + w * 32 + mi * 16 + q4 * 4 + r;
        size_t base = ((size_t)(b * 2048 + prow)) * 1024 + h * 64;
#pragma unroll
        for (int nt = 0; nt < 4; nt++) A[base + nt * 16 + l15] = f2bf(accO[mi][nt][r] * inv);
      }
  }
}

extern "C" void kernel_launch(void* const* d_in, const int* in_sizes, int n_in,
                              void* d_out, int out_size, void* d_ws, size_t ws_size,
                              hipStream_t stream) {
  const float* X  = (const float*)d_in[0];  // residual_stream [2][2048][1024]
  const float* Wq = (const float*)d_in[1];  // weight_query [16][1024][64]
  const float* Wk = (const float*)d_in[2];  // weight_key   [16][1024][64]
  const float* Wv = (const float*)d_in[3];  // weight_value [16][1024][64]
  const float* Wo = (const float*)d_in[4];  // weight_out   [1024][1024]
  float* out = (float*)d_out;               // [2][2048][1024] f32

  // WqT,WkT,WvT contiguous -> one BT stack [3072][1024] for the fused QKV GEMM.
  u16* ws = (u16*)d_ws;
  u16* WqT = ws;                    // [16][64][1024]
  u16* WoT = WqT + 3145728;         // [1024][1024]
  u16* Xb  = WoT + 1048576;         // [4096][1024] bf16 (dead after qkv)
  u16* Qb  = Xb + 4194304;          // [32][2048][64]
  u16* Kb  = Qb + 4194304;          // [32][2048][64]
  u16* VT2 = Kb + 4194304;          // [32][32][64][64] tile-blocked
  u16* Ab  = Xb;                    // aliases Xb; total 40 MB

  xcvt_k<<<dim3(2048), 256, 0, stream>>>(X, Xb);
  transpose_qkv_k<<<dim3(16, 1, 48), 256, 0, stream>>>(Wq, Wk, Wv, WqT);
  transpose_cvt_k<<<dim3(16, 16, 1), 256, 0, stream>>>(Wo, WoT, 1024, 1024);

  qkv_gemm128_k<<<dim3(32, 24), 256, 0, stream>>>(Xb, WqT, Qb, Kb, VT2);
  attn_k<<<dim3(8, 16, 2), 256, 0, stream>>>(Qb, Kb, VT2, Ab);
  out_gemm128_k<<<dim3(32, 8), 256, 0, stream>>>(Ab, WoT, out);
}

// Round 3
// 210.657 us; speedup vs baseline: 1.0775x; 1.0775x over previous
//
#include <hip/hip_runtime.h>
#include <hip/hip_bf16.h>
#include <stdint.h>

// MultiHeadAttention: B=2, P=2048, D_MODEL=1024, H=16, D=64, causal.
//
// R14: (a) attn_k: QBLK=128 kept (halved FETCH confirmed in R13) but one
// q-tile per block -> 512 blocks, 2/CU (R13's 1/CU exposed every barrier
// drain: per-iter cost 2.2x). Blocks c and c+256 co-reside -> qt = b?15-pr:pr
// balances each CU at 36 iters. K/V staging now global_load_lds (async DMA,
// no reg round-trip, no LDS-write instrs) with both-sides XOR swizzle
// (rule #21): linear LDS dest, source chunk ^= row&7, read chunk ^= l15&7
// -> fragment ds_read_b128 is <=2-way instead of 16-way at 128B rows.
// P slab stride 72 (2-way writes, alignment-safe). (b) gemm128_core: same
// both-sides swizzle on As/Bs (R13's linear [128][64] reads were 16-way).

typedef __bf16 bf16x8 __attribute__((ext_vector_type(8)));
typedef float f32x4 __attribute__((ext_vector_type(4)));
typedef unsigned short u16;

__device__ __forceinline__ u16 f2bf(float f) {
  unsigned u = __float_as_uint(f);
  u += 0x7fffu + ((u >> 16) & 1u);
  return (u16)(u >> 16);
}

// ---- X f32 -> bf16 (coalesced, 8 elems/thread) ----
__global__ __launch_bounds__(256) void xcvt_k(const float* __restrict__ in,
                                              u16* __restrict__ out) {
  int i = (blockIdx.x * 256 + threadIdx.x) * 8;
  float4 f0 = *reinterpret_cast<const float4*>(in + i);
  float4 f1 = *reinterpret_cast<const float4*>(in + i + 4);
  u16 tmp[8] = {f2bf(f0.x), f2bf(f0.y), f2bf(f0.z), f2bf(f0.w),
                f2bf(f1.x), f2bf(f1.y), f2bf(f1.z), f2bf(f1.w)};
  *reinterpret_cast<uint4*>(out + i) = *reinterpret_cast<uint4*>(tmp);
}

// ---- generic weight transpose+convert: in f32 [B][R][C] -> out bf16 [B][C][R] ----
__global__ __launch_bounds__(256) void transpose_cvt_k(const float* __restrict__ in,
                                                       u16* __restrict__ out,
                                                       int R, int C) {
  __shared__ u16 tile[64][80];
  int b = blockIdx.z;
  int r0 = blockIdx.x * 64, c0 = blockIdx.y * 64;
  const float* ip = in + (size_t)b * R * C;
  u16* op = out + (size_t)b * R * C;
  int t = threadIdx.x;
  int r = t >> 2, cb = (t & 3) * 16;
  const float4* src = reinterpret_cast<const float4*>(ip + (size_t)(r0 + r) * C + c0 + cb);
  u16 tmp[16];
#pragma unroll
  for (int v = 0; v < 4; v++) {
    float4 f = src[v];
    tmp[v * 4 + 0] = f2bf(f.x);
    tmp[v * 4 + 1] = f2bf(f.y);
    tmp[v * 4 + 2] = f2bf(f.z);
    tmp[v * 4 + 3] = f2bf(f.w);
  }
  *reinterpret_cast<uint4*>(&tile[r][cb]) = *reinterpret_cast<uint4*>(&tmp[0]);
  *reinterpret_cast<uint4*>(&tile[r][cb + 8]) = *reinterpret_cast<uint4*>(&tmp[8]);
  __syncthreads();
  int c = t >> 2, rb = (t & 3) * 16;
  uint4 outv[2];
  u16* tp = reinterpret_cast<u16*>(outv);
#pragma unroll
  for (int j = 0; j < 16; j++) tp[j] = tile[rb + j][c];
  uint4* dst = reinterpret_cast<uint4*>(op + (size_t)(c0 + c) * R + r0 + rb);
  dst[0] = outv[0];
  dst[1] = outv[1];
}

// ---- fused q/k/v weight transpose: z = 0..47 -> (sel = z>>4, head = z&15) ----
__global__ __launch_bounds__(256) void transpose_qkv_k(const float* __restrict__ Wq,
                                                       const float* __restrict__ Wk,
                                                       const float* __restrict__ Wv,
                                                       u16* __restrict__ outBase) {
  __shared__ u16 tile[64][80];
  int z = blockIdx.z;
  int sel = z >> 4, head = z & 15;
  const float* W = (sel == 0) ? Wq : (sel == 1 ? Wk : Wv);
  const float* ip = W + (size_t)head * 65536;           // [1024][64]
  u16* op = outBase + (size_t)sel * 1048576 + (size_t)head * 65536;  // [64][1024]
  int r0 = blockIdx.x * 64;                              // row block in R=1024
  int t = threadIdx.x;
  int r = t >> 2, cb = (t & 3) * 16;
  const float4* src = reinterpret_cast<const float4*>(ip + (size_t)(r0 + r) * 64 + cb);
  u16 tmp[16];
#pragma unroll
  for (int v = 0; v < 4; v++) {
    float4 f = src[v];
    tmp[v * 4 + 0] = f2bf(f.x);
    tmp[v * 4 + 1] = f2bf(f.y);
    tmp[v * 4 + 2] = f2bf(f.z);
    tmp[v * 4 + 3] = f2bf(f.w);
  }
  *reinterpret_cast<uint4*>(&tile[r][cb]) = *reinterpret_cast<uint4*>(&tmp[0]);
  *reinterpret_cast<uint4*>(&tile[r][cb + 8]) = *reinterpret_cast<uint4*>(&tmp[8]);
  __syncthreads();
  int c = t >> 2, rb = (t & 3) * 16;
  uint4 outv[2];
  u16* tp = reinterpret_cast<u16*>(outv);
#pragma unroll
  for (int j = 0; j < 16; j++) tp[j] = tile[rb + j][c];
  uint4* dst = reinterpret_cast<uint4*>(op + (size_t)c * 1024 + r0 + rb);
  dst[0] = outv[0];
  dst[1] = outv[1];
}

// ---- direct global->LDS DMA, 16B per lane (dest = wave-uniform base + lane*16) ----
__device__ __forceinline__ void gload16(const u16* g, u16* l) {
  __builtin_amdgcn_global_load_lds(
      (__attribute__((address_space(1))) void*)(g),
      (__attribute__((address_space(3))) void*)(l), 16, 0, 0);
}

// ============ 128x128 GEMM core (m97 rung + both-sides XOR swizzle) ============
// LDS rows are 128B (linear, as gload_lds needs). Swizzle: 16B chunk p at row r
// holds global chunk p ^ (r&7); stage pre-swizzles the per-lane SOURCE col,
// reads XOR their chunk index. Fragment reads drop 16-way -> 2-way.
__device__ __forceinline__ void gemm128_core(const u16* __restrict__ A,
                                             const u16* __restrict__ BT,
                                             int m0, int n0,
                                             f32x4 (&acc)[4][4]) {
  __shared__ __align__(16) u16 As[128][64];
  __shared__ __align__(16) u16 Bs[128][64];
  int t = threadIdx.x, l = t & 63;
  int w = t >> 6, wm = w & 1, wn = w >> 1;
  int l15 = l & 15, q4 = l >> 4;
  int r8 = l >> 3;                   // row within an 8-row gload group
  int cs = ((l & 7) ^ r8) * 8;       // pre-swizzled source chunk (u16 units)
  int swz = l15 & 7;                 // read-side row XOR key
  int srow = w * 32 + r8;
  const u16* ga = A + (size_t)(m0 + srow) * 1024 + cs;
  const u16* gb = BT + (size_t)(n0 + srow) * 1024 + cs;
  f32x4 z4 = {0.f, 0.f, 0.f, 0.f};
#pragma unroll
  for (int mi = 0; mi < 4; mi++)
#pragma unroll
    for (int nt = 0; nt < 4; nt++) acc[mi][nt] = z4;

  for (int k0 = 0; k0 < 1024; k0 += 64) {
    __syncthreads();
#pragma unroll
    for (int i = 0; i < 4; i++) {
      gload16(ga + (size_t)(i * 8) * 1024 + k0, &As[w * 32 + i * 8][0]);
      gload16(gb + (size_t)(i * 8) * 1024 + k0, &Bs[w * 32 + i * 8][0]);
    }
    __syncthreads();   // vmcnt(0) drain lands the DMA
#pragma unroll
    for (int kk = 0; kk < 2; kk++) {
      bf16x8 af[4], bfr[4];
#pragma unroll
      for (int mi = 0; mi < 4; mi++)
        af[mi] = *reinterpret_cast<const bf16x8*>(
            &As[wm * 64 + mi * 16 + l15][((kk * 4 + q4) ^ swz) * 8]);
#pragma unroll
      for (int nt = 0; nt < 4; nt++)
        bfr[nt] = *reinterpret_cast<const bf16x8*>(
            &Bs[wn * 64 + nt * 16 + l15][((kk * 4 + q4) ^ swz) * 8]);
#pragma unroll
      for (int mi = 0; mi < 4; mi++)
#pragma unroll
        for (int nt = 0; nt < 4; nt++)
          acc[mi][nt] = __builtin_amdgcn_mfma_f32_16x16x32_bf16(af[mi], bfr[nt], acc[mi][nt], 0, 0, 0);
    }
  }
}

// QKV: A=Xb [4096][1024], BT=[WqT|WkT|WvT] [3072][1024]; grid (32, 24).
// V written tile-blocked: VT2[bh][ktile(32)][d(64)][pc(64)].
__global__ __launch_bounds__(256) void qkv_gemm128_k(const u16* __restrict__ A,
                                                     const u16* __restrict__ BT,
                                                     u16* __restrict__ Q,
                                                     u16* __restrict__ K,
                                                     u16* __restrict__ VT2) {
  const float QSCALE = 0.125f * 1.44269504088896340736f;  // (1/sqrt(64))*log2(e)
  int m0 = blockIdx.x * 128, n0 = blockIdx.y * 128;
  f32x4 acc[4][4];
  gemm128_core(A, BT, m0, n0, acc);
  int t = threadIdx.x, l = t & 63;
  int w = t >> 6, wm = w & 1, wn = w >> 1;
  int l15 = l & 15, q4 = l >> 4;
#pragma unroll
  for (int mi = 0; mi < 4; mi++) {
#pragma unroll
    for (int nt = 0; nt < 4; nt++) {
#pragma unroll
      for (int r = 0; r < 4; r++) {
        int m = m0 + wm * 64 + mi * 16 + q4 * 4 + r;
        int n = n0 + wn * 64 + nt * 16 + l15;
        int wsel = n >> 10, h = (n >> 6) & 15, d = n & 63;
        int b = m >> 11, p = m & 2047;
        size_t bh = (size_t)(b * 16 + h);
        float v = acc[mi][nt][r];
        if (wsel == 0)
          Q[(bh * 2048 + p) * 64 + d] = f2bf(v * QSCALE);
        else if (wsel == 1)
          K[(bh * 2048 + p) * 64 + d] = f2bf(v);
        else
          VT2[((bh * 32 + (p >> 6)) * 64 + d) * 64 + (p & 63)] = f2bf(v);
      }
    }
  }
}

// OUT: A=Ab [4096][1024], BT=WoT [1024][1024], O f32; grid (32, 8).
__global__ __launch_bounds__(256) void out_gemm128_k(const u16* __restrict__ A,
                                                     const u16* __restrict__ BT,
                                                     float* __restrict__ O) {
  int m0 = blockIdx.x * 128, n0 = blockIdx.y * 128;
  f32x4 acc[4][4];
  gemm128_core(A, BT, m0, n0, acc);
  int t = threadIdx.x, l = t & 63;
  int w = t >> 6, wm = w & 1, wn = w >> 1;
  int l15 = l & 15, q4 = l >> 4;
#pragma unroll
  for (int mi = 0; mi < 4; mi++) {
#pragma unroll
    for (int nt = 0; nt < 4; nt++) {
#pragma unroll
      for (int r = 0; r < 4; r++) {
        int m = m0 + wm * 64 + mi * 16 + q4 * 4 + r;
        int n = n0 + wn * 64 + nt * 16 + l15;
        O[(size_t)m * 1024 + n] = acc[mi][nt][r];
      }
    }
  }
}

// -------- flash attention: QBLK=128, 1 q-tile/block, gload_lds staging --------
// grid (16,16,2) = 512 blocks -> 2/CU. Blocks c and c+256 co-reside (round-robin
// heuristic): qt = b?15-pr:pr makes each CU's pair sum to 36 kt-iters.
// Per kt-iter: issue next tile's 4 gload_lds DMAs into buf^1 -> QK -> softmax
// -> PV -> one __syncthreads (vmcnt drain lands the prefetch).
__global__ __launch_bounds__(256) void attn_k(const u16* __restrict__ Q,
                                              const u16* __restrict__ K,
                                              const u16* __restrict__ VT2,
                                              u16* __restrict__ A) {
  __shared__ __align__(16) u16 Ks[2][64][64];
  __shared__ __align__(16) u16 Vs[2][64][64];
  __shared__ u16 P[4][32][72];   // wave-private; stride 72: 2-way writes, 16B-ish reads
  int pr = blockIdx.x, h = blockIdx.y, b = blockIdx.z;
  int qt = b ? (15 - pr) : pr;
  size_t bh = (size_t)(b * 16 + h);
  const u16* Qp = Q + bh * 2048 * 64;
  const u16* Kp = K + bh * 2048 * 64;
  const u16* Vt = VT2 + bh * 32 * 64 * 64;   // [kt][d][64]
  int t = threadIdx.x, l = t & 63, w = t >> 6;
  int l15 = l & 15, q4 = l >> 4;
  int r8 = l >> 3, cs = ((l & 7) ^ r8) * 8;  // staging source pre-swizzle
  int swz = l15 & 7;                          // fragment-read XOR key
  const float NEG = -1e30f;
  f32x4 z4 = {0.f, 0.f, 0.f, 0.f};
  int nkt = 2 * qt + 2;
  // wave w stages rows [w*16, w*16+16) of both tiles; 2 gloads each of K and V
  const u16* kbase = Kp + (size_t)(w * 16 + r8) * 64 + cs;
  const u16* vbase = Vt + (size_t)(w * 16 + r8) * 64 + cs;

  int qr0 = qt * 128 + w * 32;
  bf16x8 qf[2][2];
#pragma unroll
  for (int mi = 0; mi < 2; mi++) {
    const u16* qp = Qp + (size_t)(qr0 + mi * 16 + l15) * 64;
    qf[mi][0] = *reinterpret_cast<const bf16x8*>(qp + q4 * 8);
    qf[mi][1] = *reinterpret_cast<const bf16x8*>(qp + 32 + q4 * 8);
  }
  f32x4 accO[2][4];
  float rs[2][4];
#pragma unroll
  for (int mi = 0; mi < 2; mi++) {
#pragma unroll
    for (int nt = 0; nt < 4; nt++) accO[mi][nt] = z4;
#pragma unroll
    for (int r = 0; r < 4; r++) rs[mi][r] = 0.f;
  }

  // prologue: DMA tile kt=0 into buffer 0
#pragma unroll
  for (int j = 0; j < 2; j++) {
    gload16(kbase + (size_t)(j * 512), &Ks[0][w * 16 + j * 8][0]);
    gload16(vbase + (size_t)(j * 512), &Vs[0][w * 16 + j * 8][0]);
  }
  __syncthreads();

  for (int kt = 0; kt < nkt; kt++) {
    int cur = kt & 1;
    if (kt < nkt - 1) {  // prefetch next tile into buf^1; lands at the barrier
      size_t off = (size_t)(kt + 1) * 4096;
#pragma unroll
      for (int j = 0; j < 2; j++) {
        gload16(kbase + off + j * 512, &Ks[cur ^ 1][w * 16 + j * 8][0]);
        gload16(vbase + off + j * 512, &Vs[cur ^ 1][w * 16 + j * 8][0]);
      }
    }

    f32x4 s[2][4];
#pragma unroll
    for (int mi = 0; mi < 2; mi++)
#pragma unroll
      for (int nt = 0; nt < 4; nt++) s[mi][nt] = z4;
    __builtin_amdgcn_s_setprio(1);
#pragma unroll
    for (int kk = 0; kk < 2; kk++) {
      bf16x8 kf[4];
#pragma unroll
      for (int nt = 0; nt < 4; nt++)
        kf[nt] = *reinterpret_cast<const bf16x8*>(
            &Ks[cur][nt * 16 + l15][((kk * 4 + q4) ^ swz) * 8]);
#pragma unroll
      for (int mi = 0; mi < 2; mi++)
#pragma unroll
        for (int nt = 0; nt < 4; nt++)
          s[mi][nt] = __builtin_amdgcn_mfma_f32_16x16x32_bf16(qf[mi][kk], kf[nt], s[mi][nt], 0, 0, 0);
    }
    __builtin_amdgcn_s_setprio(0);
    if (kt >= 2 * qt) {  // causal masking (last two kv tiles of this q tile)
      int colbase = (kt - 2 * qt) * 64;
      int rowl = w * 32 + q4 * 4;
#pragma unroll
      for (int mi = 0; mi < 2; mi++)
#pragma unroll
        for (int nt = 0; nt < 4; nt++)
#pragma unroll
          for (int r = 0; r < 4; r++)
            if (colbase + nt * 16 + l15 > rowl + mi * 16 + r) s[mi][nt][r] = NEG;
    }
    // fixed-max softmax numerator: p = 2^s (s already log2-domain)
#pragma unroll
    for (int mi = 0; mi < 2; mi++)
#pragma unroll
      for (int nt = 0; nt < 4; nt++)
#pragma unroll
        for (int r = 0; r < 4; r++) {
          float p = exp2f(s[mi][nt][r]);
          rs[mi][r] += p;
          P[w][mi * 16 + q4 * 4 + r][nt * 16 + l15] = f2bf(p);
        }
    __builtin_amdgcn_s_setprio(1);
#pragma unroll
    for (int kk = 0; kk < 2; kk++) {
      bf16x8 pa[2];
#pragma unroll
      for (int mi = 0; mi < 2; mi++)
        pa[mi] = *reinterpret_cast<const bf16x8*>(&P[w][mi * 16 + l15][kk * 32 + q4 * 8]);
#pragma unroll
      for (int nt = 0; nt < 4; nt++) {
        bf16x8 vf = *reinterpret_cast<const bf16x8*>(
            &Vs[cur][nt * 16 + l15][((kk * 4 + q4) ^ swz) * 8]);
#pragma unroll
        for (int mi = 0; mi < 2; mi++)
          accO[mi][nt] = __builtin_amdgcn_mfma_f32_16x16x32_bf16(pa[mi], vf, accO[mi][nt], 0, 0, 0);
      }
    }
    __builtin_amdgcn_s_setprio(0);
    __syncthreads();  // single barrier: LDS reads done + prefetch DMA landed
  }

#pragma unroll
  for (int mi = 0; mi < 2; mi++)
#pragma unroll
    for (int r = 0; r < 4; r++) {
      float v = rs[mi][r];
#pragma unroll
      for (int sh = 1; sh < 16; sh <<= 1) v += __shfl_xor(v, sh, 64);
      float inv = 1.f / v;
      int prow = qt * 128 + w * 32 + mi * 16 + q4 * 4 + r;
      size_t base = ((size_t)(b * 2048 + prow)) * 1024 + h * 64;
#pragma unroll
      for (int nt = 0; nt < 4; nt++) A[base + nt * 16 + l15] = f2bf(accO[mi][nt][r] * inv);
    }
}

extern "C" void kernel_launch(void* const* d_in, const int* in_sizes, int n_in,
                              void* d_out, int out_size, void* d_ws, size_t ws_size,
                              hipStream_t stream) {
  const float* X  = (const float*)d_in[0];  // residual_stream [2][2048][1024]
  const float* Wq = (const float*)d_in[1];  // weight_query [16][1024][64]
  const float* Wk = (const float*)d_in[2];  // weight_key   [16][1024][64]
  const float* Wv = (const float*)d_in[3];  // weight_value [16][1024][64]
  const float* Wo = (const float*)d_in[4];  // weight_out   [1024][1024]
  float* out = (float*)d_out;               // [2][2048][1024] f32

  // WqT,WkT,WvT contiguous -> one BT stack [3072][1024] for the fused QKV GEMM.
  u16* ws = (u16*)d_ws;
  u16* WqT = ws;                    // [16][64][1024]
  u16* WoT = WqT + 3145728;         // [1024][1024]
  u16* Xb  = WoT + 1048576;         // [4096][1024] bf16 (dead after qkv)
  u16* Qb  = Xb + 4194304;          // [32][2048][64]
  u16* Kb  = Qb + 4194304;          // [32][2048][64]
  u16* VT2 = Kb + 4194304;          // [32][32][64][64] tile-blocked
  u16* Ab  = Xb;                    // aliases Xb; total 40 MB

  xcvt_k<<<dim3(2048), 256, 0, stream>>>(X, Xb);
  transpose_qkv_k<<<dim3(16, 1, 48), 256, 0, stream>>>(Wq, Wk, Wv, WqT);
  transpose_cvt_k<<<dim3(16, 16, 1), 256, 0, stream>>>(Wo, WoT, 1024, 1024);

  qkv_gemm128_k<<<dim3(32, 24), 256, 0, stream>>>(Xb, WqT, Qb, Kb, VT2);
  attn_k<<<dim3(16, 16, 2), 256, 0, stream>>>(Qb, Kb, VT2, Ab);
  out_gemm128_k<<<dim3(32, 8), 256, 0, stream>>>(Ab, WoT, out);
}